// Round 5
// baseline (269.517 us; speedup 1.0000x reference)
//
#include <hip/hip_runtime.h>
#include <hip/hip_bf16.h>

// PinSageConv on MI355X — round 12.
// qgemm v12: persistent 2-phase async pipeline.
//  - v11 failed because regalloc (84 VGPR) re-serialized the f32 load batch:
//    <1KB outstanding per block, 1.16 TB/s, per-block latency ~23 µs.
//  - v12: grid 256 x 512thr (8 waves, 1 block/CU). Per block: loop ~6 tiles.
//    Per tile: __syncthreads (drains prev stage) -> issue 8x global_load_lds
//    (f32, 1KB row per instr, padded 1040B LDS rows) for tile t+1 into the
//    other buffer -> compute tile t (ds_read f32 -> cvt -> MFMA, B RESIDENT
//    in 64 VGPR loaded once, bias resident) -> fp8 epilogue. Stage of t+1
//    transfers under compute of t; barrier drain only pays the remainder.
//  - f32-in-LDS removes both the hcvt pre-pass (r3) and the VGPR round-trip
//    (v8/v11); conversion at fragment-build time = fgemm's verified A path.
// aggk/fgemm/normk/wcvt unchanged (one structural change per round).
// Workspace: q_fp8[100000][256] @0 (25.6MB) | aggF[20000][256] f32 @25.6MB
//            | QwB bf16 @46,080,000 | WwB bf16 @46,211,072.

#define M_TOTAL 100000
#define N_NODES 20000
#define T_NB    50
#define IN_F    256
#define HID_F   256
#define OUT_F   256
#define KCAT    512

typedef __bf16 bf16x8 __attribute__((ext_vector_type(8)));
typedef float  floatx4 __attribute__((ext_vector_type(4)));
typedef float  v2f     __attribute__((ext_vector_type(2)));

__device__ __forceinline__ unsigned short f2bf(float f) {
    unsigned int u = __float_as_uint(f);
    u += 0x7fffu + ((u >> 16) & 1u);          // RTNE
    return (unsigned short)(u >> 16);
}
__device__ __forceinline__ void gload16(const void* g, void* l) {
    __builtin_amdgcn_global_load_lds(
        (const __attribute__((address_space(1))) unsigned int*)g,
        (__attribute__((address_space(3))) unsigned int*)l, 16, 0, 0);
}
__device__ __forceinline__ bf16x8 cvt_frag(float4 a, float4 b) {
    bf16x8 r;
    r[0] = (__bf16)a.x; r[1] = (__bf16)a.y; r[2] = (__bf16)a.z; r[3] = (__bf16)a.w;
    r[4] = (__bf16)b.x; r[5] = (__bf16)b.y; r[6] = (__bf16)b.z; r[7] = (__bf16)b.w;
    return r;
}

// ---------------------------------------------------------------------------
// Kernel 0: convert Qw (65536 f32) and Ww (131072 f32) to bf16.
// ---------------------------------------------------------------------------
__global__ __launch_bounds__(256)
void wcvt(const float* __restrict__ Qw, const float* __restrict__ Ww,
          unsigned short* __restrict__ QwB, unsigned short* __restrict__ WwB) {
    const int e = (blockIdx.x * 256 + threadIdx.x) * 4;
    float4 v;
    unsigned short* dst;
    if (e < 65536) { v = *(const float4*)(Qw + e);           dst = QwB + e; }
    else           { v = *(const float4*)(Ww + (e - 65536)); dst = WwB + (e - 65536); }
    ushort4 s;
    s.x = f2bf(v.x); s.y = f2bf(v.y); s.z = f2bf(v.z); s.w = f2bf(v.w);
    *(ushort4*)dst = s;
}

// ---------------------------------------------------------------------------
// Kernel 1: q = fp8(relu(h @ Qw.T + Qb)).  M=100000 N=256(full) K=256.
// Persistent: 256 blocks x 512 threads (8 waves), ~6 tiles of 64 rows each.
// LDS: A dbuf 2 x [64][260] f32 (padded rows, 1040B) + epi 8 x 512 dwords.
// Wave wv owns 32 output cols (wc = wv*32): B slice (16 bf16x8) + bias
// resident in registers. Swapped-operand MFMA (verified): lane owns row
// mt*16+fr, cols wc + nt*16 + quad*4 .. +3.
// ---------------------------------------------------------------------------
__global__ __launch_bounds__(512, 2)
void qgemm(const float* __restrict__ h, const unsigned short* __restrict__ QwB,
           const float* __restrict__ Qb, unsigned char* __restrict__ q) {
    __shared__ float smem[2 * 16640 + 4096];   // 2x(64x260 f32) + 16KB epi = 149504 B

    const int tid  = threadIdx.x;
    const int lane = tid & 63;
    const int wv   = tid >> 6;             // 0..7
    const int wc   = wv << 5;              // wave's 32-col (n) slice
    const int quad = lane >> 4;
    const int fr   = lane & 15;

    // --- Resident B: wave's 64x... 32(n) x 256(k) slice = 16 fragments.
    bf16x8 B[8][2];
    {
        const unsigned short* bp = QwB + (size_t)(wc + fr) * IN_F + quad * 8;
#pragma unroll
        for (int nt = 0; nt < 2; ++nt)
#pragma unroll
            for (int kb = 0; kb < 8; ++kb)
                B[kb][nt] = *(const bf16x8*)(bp + nt * 16 * IN_F + kb * 32);
    }
    // --- Resident bias: cols wc + nt*16 + quad*4 .. +3.
    float4 bias[2];
#pragma unroll
    for (int nt = 0; nt < 2; ++nt)
        bias[nt] = *(const float4*)(Qb + wc + nt * 16 + quad * 4);

    const int NT = (M_TOTAL + 63) >> 6;    // 1563 tiles

    // Stage one 64-row tile (f32) into buffer b. One instr = one 1KB row:
    // dest = uniform(row base) + lane*16 (gload_lds rule), src coalesced.
    auto stage = [&](int tile, int b) {
        const int r0 = tile << 6;
        char* dbase = (char*)(smem + b * 16640);
#pragma unroll
        for (int i = 0; i < 8; ++i) {
            const int r  = wv + (i << 3);
            const int gr = min(r0 + r, M_TOTAL - 1);
            gload16(h + (size_t)gr * IN_F + (lane << 2), dbase + r * 1040 + (lane << 4));
        }
    };

    int t = blockIdx.x;
    int n = 0;
    stage(t, 0);                           // prologue

    for (;;) {
        __syncthreads();                   // drains vmcnt -> buf[n] ready; buf[n^1] free
        const int tn = t + (int)gridDim.x;
        if (tn < NT) stage(tn, n ^ 1);     // async: transfers under compute below
        __builtin_amdgcn_sched_barrier(0); // pin stage issue before compute

        const float* A = smem + n * 16640;
        floatx4 acc[2][4];                 // [nt][mt]
#pragma unroll
        for (int i = 0; i < 2; ++i)
#pragma unroll
            for (int j = 0; j < 4; ++j)
                acc[i][j] = (floatx4){0.f, 0.f, 0.f, 0.f};

#pragma unroll
        for (int kb = 0; kb < 8; ++kb) {
            bf16x8 av[4];
#pragma unroll
            for (int mt = 0; mt < 4; ++mt) {
                const int r = mt * 16 + fr;
                const float* pr = A + r * 260 + kb * 32 + quad * 8;
                const float4 p0 = *(const float4*)pr;
                const float4 p1 = *(const float4*)(pr + 4);
                av[mt] = cvt_frag(p0, p1);
            }
#pragma unroll
            for (int nt = 0; nt < 2; ++nt)
#pragma unroll
                for (int mt = 0; mt < 4; ++mt)
                    acc[nt][mt] = __builtin_amdgcn_mfma_f32_16x16x32_bf16(B[kb][nt], av[mt], acc[nt][mt], 0, 0, 0);
        }

        // --- Epilogue: pack fp8 dwords -> per-wave LDS region -> uint4 stores.
        unsigned* const epi = (unsigned*)(smem + 2 * 16640) + (wv << 9);  // 512 dw
#pragma unroll
        for (int nt = 0; nt < 2; ++nt)
#pragma unroll
            for (int mt = 0; mt < 4; ++mt) {
                float v0 = fmaxf(acc[nt][mt][0] + bias[nt].x, 0.f);
                float v1 = fmaxf(acc[nt][mt][1] + bias[nt].y, 0.f);
                float v2 = fmaxf(acc[nt][mt][2] + bias[nt].z, 0.f);
                float v3 = fmaxf(acc[nt][mt][3] + bias[nt].w, 0.f);
                unsigned wpk = (unsigned)__builtin_amdgcn_cvt_pk_fp8_f32(v0, v1, 0, false);
                wpk = (unsigned)__builtin_amdgcn_cvt_pk_fp8_f32(v2, v3, wpk, true);
                const int r = mt * 16 + fr;
                epi[(r << 3) + (((nt ^ (r & 1)) << 2) + quad)] = wpk;
            }
        __asm volatile("s_waitcnt lgkmcnt(0)" ::: "memory");  // in-wave write->read

        const int row0 = t << 6;
#pragma unroll
        for (int i = 0; i < 2; ++i) {
            const int r   = i * 32 + (lane >> 1);
            const int seg = lane & 1;
            const uint4 val = *(const uint4*)(epi + (r << 3) + ((seg ^ (r & 1)) << 2));
            const int gr = row0 + r;
            if (gr < M_TOTAL)
                *(uint4*)(q + (size_t)gr * HID_F + wc + seg * 16) = val;
        }

        if (tn >= NT) break;
        t = tn; n ^= 1;
    }
}

// ---------------------------------------------------------------------------
// Kernel 2: aggF[n] = sum_t w[n,t]*q[nb[n,t]] / sum_t w[n,t]  (fp32 out).
// One wave/node; 4 neighbors per load instruction (quarter-wave each,
// 16B/lane uint4). 13 iterations (t = 4i + sub, lanes with t>=50 carry w=0).
// ---------------------------------------------------------------------------
__global__ __launch_bounds__(256)
void aggk(const unsigned char* __restrict__ q, const int* __restrict__ nb,
          const float* __restrict__ w, float* __restrict__ aggF) {
    const int node = blockIdx.x * 4 + (threadIdx.x >> 6);
    const int lane = threadIdx.x & 63;

    int   idx_l = 0;
    float w_l   = 0.f;
    if (lane < T_NB) {
        idx_l = nb[(size_t)node * T_NB + lane];
        w_l   = w[(size_t)node * T_NB + lane];
    }
    float sw = w_l;
#pragma unroll
    for (int off = 32; off > 0; off >>= 1)
        sw += __shfl_xor(sw, off, 64);

    const int sub = lane >> 4;       // neighbor slot within group of 4
    const int cg  = lane & 15;       // which 16B column chunk of the row
    float a[16];
#pragma unroll
    for (int j = 0; j < 16; ++j) a[j] = 0.f;

#pragma unroll
    for (int i = 0; i < 13; ++i) {
        const int   t   = 4 * i + sub;              // 0..51; t>=50 has w=0,idx=0
        const int   idx = __shfl(idx_l, t, 64);
        const float wt  = __shfl(w_l, t, 64);
        const uint4 u   = *(const uint4*)(q + (size_t)idx * HID_F + cg * 16);
        v2f p;
        p = __builtin_amdgcn_cvt_pk_f32_fp8(u.x, false); a[0]  += wt * p[0]; a[1]  += wt * p[1];
        p = __builtin_amdgcn_cvt_pk_f32_fp8(u.x, true);  a[2]  += wt * p[0]; a[3]  += wt * p[1];
        p = __builtin_amdgcn_cvt_pk_f32_fp8(u.y, false); a[4]  += wt * p[0]; a[5]  += wt * p[1];
        p = __builtin_amdgcn_cvt_pk_f32_fp8(u.y, true);  a[6]  += wt * p[0]; a[7]  += wt * p[1];
        p = __builtin_amdgcn_cvt_pk_f32_fp8(u.z, false); a[8]  += wt * p[0]; a[9]  += wt * p[1];
        p = __builtin_amdgcn_cvt_pk_f32_fp8(u.z, true);  a[10] += wt * p[0]; a[11] += wt * p[1];
        p = __builtin_amdgcn_cvt_pk_f32_fp8(u.w, false); a[12] += wt * p[0]; a[13] += wt * p[1];
        p = __builtin_amdgcn_cvt_pk_f32_fp8(u.w, true);  a[14] += wt * p[0]; a[15] += wt * p[1];
    }
    // lanes {cg, cg+16, cg+32, cg+48} hold partial sums of the same 16 cols
#pragma unroll
    for (int j = 0; j < 16; ++j) {
        a[j] += __shfl_xor(a[j], 16, 64);
        a[j] += __shfl_xor(a[j], 32, 64);
    }

    if (lane < 16) {
        const float inv = 1.0f / sw;
        float* dst = aggF + (size_t)node * HID_F + cg * 16;
#pragma unroll
        for (int k = 0; k < 4; ++k) {
            float4 o = make_float4(a[4 * k] * inv, a[4 * k + 1] * inv,
                                   a[4 * k + 2] * inv, a[4 * k + 3] * inv);
            *(float4*)(dst + 4 * k) = o;
        }
    }
}

// ---------------------------------------------------------------------------
// Kernel 3: out = relu(concat(h[nodeset], aggF) @ Ww.T + Wb).  M=20000 N=256 K=512.
// 64x128 tile, BK=64, async staging (A gathered fp32, B bf16). Wave = 64x32.
// ---------------------------------------------------------------------------
__global__ __launch_bounds__(256)
void fgemm(const float* __restrict__ h, const int* __restrict__ nodeset,
           const float* __restrict__ aggF, const unsigned short* __restrict__ WwB,
           const float* __restrict__ Wb, float* __restrict__ out) {
    __shared__ char smem[32768];
    float* ldsA = (float*)smem;                              // 64 rows x 16 chunks
    unsigned short* ldsB = (unsigned short*)(smem + 16384);  // 128 rows x 8 chunks

    const int tid  = threadIdx.x;
    const int row0 = blockIdx.x * 64;
    const int n0   = blockIdx.y * 128;
    const int lane = tid & 63;
    const int wv   = tid >> 6;
    const int wc   = wv << 5;
    const int fr   = lane & 15;
    const int fk   = (lane >> 4) << 3;
    const int ca   = fk >> 2;
    const int cbB  = fk >> 3;

    int nsrow[4];
#pragma unroll
    for (int i = 0; i < 4; ++i) {
        const int row = (tid + i * 256) >> 4;
        nsrow[i] = nodeset[min(row0 + row, N_NODES - 1)];
    }

    floatx4 acc[4][2];
#pragma unroll
    for (int i = 0; i < 4; ++i)
#pragma unroll
        for (int j = 0; j < 2; ++j)
            acc[i][j] = (floatx4){0.f, 0.f, 0.f, 0.f};

    for (int kb = 0; kb < 8; ++kb) {
        if (kb) __syncthreads();
#pragma unroll
        for (int i = 0; i < 4; ++i) {
            const int L   = tid + i * 256;
            const int row = L >> 4;
            const int cg  = (L & 15) ^ (row & 15);
            const float* src = (kb < 4)
                ? h    + (size_t)nsrow[i] * IN_F + kb * 64 + cg * 4
                : aggF + (size_t)min(row0 + row, N_NODES - 1) * HID_F + (kb - 4) * 64 + cg * 4;
            gload16(src, smem + L * 16);
        }
#pragma unroll
        for (int i = 0; i < 4; ++i) {
            const int L   = tid + i * 256;
            const int row = L >> 3;
            const int cg  = (L & 7) ^ (row & 7);
            gload16(WwB + (size_t)(n0 + row) * KCAT + kb * 64 + cg * 8, smem + 16384 + L * 16);
        }
        __syncthreads();

#pragma unroll
        for (int ks = 0; ks < 2; ++ks) {
            bf16x8 av[4], bv[2];
#pragma unroll
            for (int mt = 0; mt < 4; ++mt) {
                const int row = mt * 16 + fr;
                const int sw  = row & 15;
                const int c0  = ks * 8 + ca;
                const float4 p0 = *(const float4*)(ldsA + (row * 16 + (c0 ^ sw)) * 4);
                const float4 p1 = *(const float4*)(ldsA + (row * 16 + ((c0 + 1) ^ sw)) * 4);
                av[mt] = cvt_frag(p0, p1);
            }
#pragma unroll
            for (int nt = 0; nt < 2; ++nt) {
                const int row = wc + nt * 16 + fr;
                const int sw  = row & 7;
                bv[nt] = *reinterpret_cast<const bf16x8*>(ldsB + row * 64 + ((ks * 4 + cbB) ^ sw) * 8);
            }
#pragma unroll
            for (int mt = 0; mt < 4; ++mt)
#pragma unroll
                for (int nt = 0; nt < 2; ++nt)
                    acc[mt][nt] = __builtin_amdgcn_mfma_f32_16x16x32_bf16(av[mt], bv[nt], acc[mt][nt], 0, 0, 0);
        }
    }

    const int erow = (lane >> 4) << 2;
    const int ecol = lane & 15;
#pragma unroll
    for (int nt = 0; nt < 2; ++nt) {
        const int gcol = n0 + wc + nt * 16 + ecol;
        const float bias = Wb[gcol];
#pragma unroll
        for (int mt = 0; mt < 4; ++mt)
#pragma unroll
            for (int r = 0; r < 4; ++r) {
                const int gr = row0 + mt * 16 + erow + r;
                if (gr < N_NODES) {
                    const float v = acc[mt][nt][r] + bias;
                    out[(size_t)gr * OUT_F + gcol] = (v > 0.f ? v : 0.f);
                }
            }
    }
}

// ---------------------------------------------------------------------------
// Kernel 4: in-place row L2 normalize. One wave per row.
// ---------------------------------------------------------------------------
__global__ __launch_bounds__(256)
void normk(float* __restrict__ out) {
    const int row = blockIdx.x * 4 + (threadIdx.x >> 6);
    const int lane = threadIdx.x & 63;
    float4 v = *(float4*)(out + (size_t)row * OUT_F + lane * 4);
    float ss = v.x * v.x + v.y * v.y + v.z * v.z + v.w * v.w;
#pragma unroll
    for (int off = 32; off > 0; off >>= 1)
        ss += __shfl_xor(ss, off, 64);
    const float s = rsqrtf(ss);
    v.x *= s; v.y *= s; v.z *= s; v.w *= s;
    *(float4*)(out + (size_t)row * OUT_F + lane * 4) = v;
}

extern "C" void kernel_launch(void* const* d_in, const int* in_sizes, int n_in,
                              void* d_out, int out_size, void* d_ws, size_t ws_size,
                              hipStream_t stream) {
    const float* h        = (const float*)d_in[0];
    const int*   nodeset  = (const int*)d_in[1];
    const int*   nb_nodes = (const int*)d_in[2];
    const float* nb_w     = (const float*)d_in[3];
    const float* Qw       = (const float*)d_in[4];
    const float* Qb       = (const float*)d_in[5];
    const float* Ww       = (const float*)d_in[6];
    const float* Wb       = (const float*)d_in[7];
    float* out = (float*)d_out;

    unsigned char*  q    = (unsigned char*)d_ws;                          // 25.6 MB
    float*          aggF = (float*)((char*)d_ws + 25600000);              // 20.48 MB
    unsigned short* QwB  = (unsigned short*)((char*)d_ws + 46080000);     // 128 KB
    unsigned short* WwB  = (unsigned short*)((char*)d_ws + 46211072);     // 256 KB

    wcvt <<<dim3(192),                    256, 0, stream>>>(Qw, Ww, QwB, WwB);
    qgemm<<<dim3(256),                    512, 0, stream>>>(h, QwB, Qb, q);
    aggk <<<dim3(N_NODES / 4),            256, 0, stream>>>(q, nb_nodes, nb_w, aggF);
    fgemm<<<dim3((N_NODES + 63) / 64, 2), 256, 0, stream>>>(h, nodeset, aggF, WwB, Wb, out);
    normk<<<dim3(N_NODES / 4),            256, 0, stream>>>(out);
}

// Round 6
// 241.409 us; speedup vs baseline: 1.1164x; 1.1164x over previous
//
#include <hip/hip_runtime.h>
#include <hip/hip_bf16.h>

// PinSageConv on MI355X — round 13.
// qgemm: EXACT revert to the round-0 harness-verified v8 (60.4 µs measured).
//   Five qgemm rewrites (v9-v12) all regressed or washed; v12's f32-padded
//   LDS rows hit 15.8M bank-conflict cycles (pad is the wrong fix for b128;
//   XOR chunk swizzle is right). v8 is the local optimum; restored verbatim.
// fgemm v2 (the one structural change this round): block now covers the FULL
//   256-col row (4 waves x 64 cols, acc 4x4), and the row L2-normalization is
//   fused in-block: per-lane ss over its 16 values -> shfl_xor 1/2/4/8 (sums
//   16 fr-cols within quad) -> per-wave ss vector in LDS -> cross-wave sum +
//   rsqrt -> scaled single write of out. Deletes the normk kernel AND out's
//   40MB re-read/re-write.
// aggk v2 (uint4 gathers) kept — measured neutral vs v1, fewer instructions.
// Workspace: q_fp8[100000][256] @0 (25.6MB) | aggF[20000][256] f32 @25.6MB
//            | QwB bf16 @46,080,000 | WwB bf16 @46,211,072.

#define M_TOTAL 100000
#define N_NODES 20000
#define T_NB    50
#define IN_F    256
#define HID_F   256
#define OUT_F   256
#define KCAT    512

typedef __bf16 bf16x8 __attribute__((ext_vector_type(8)));
typedef float  floatx4 __attribute__((ext_vector_type(4)));
typedef float  v2f     __attribute__((ext_vector_type(2)));

__device__ __forceinline__ unsigned short f2bf(float f) {
    unsigned int u = __float_as_uint(f);
    u += 0x7fffu + ((u >> 16) & 1u);          // RTNE
    return (unsigned short)(u >> 16);
}
__device__ __forceinline__ void gload16(const void* g, void* l) {
    __builtin_amdgcn_global_load_lds(
        (const __attribute__((address_space(1))) unsigned int*)g,
        (__attribute__((address_space(3))) unsigned int*)l, 16, 0, 0);
}
__device__ __forceinline__ bf16x8 cvt_frag(float4 a, float4 b) {
    bf16x8 r;
    r[0] = (__bf16)a.x; r[1] = (__bf16)a.y; r[2] = (__bf16)a.z; r[3] = (__bf16)a.w;
    r[4] = (__bf16)b.x; r[5] = (__bf16)b.y; r[6] = (__bf16)b.z; r[7] = (__bf16)b.w;
    return r;
}

// ---------------------------------------------------------------------------
// Kernel 0: convert Qw (65536 f32) and Ww (131072 f32) to bf16.
// ---------------------------------------------------------------------------
__global__ __launch_bounds__(256)
void wcvt(const float* __restrict__ Qw, const float* __restrict__ Ww,
          unsigned short* __restrict__ QwB, unsigned short* __restrict__ WwB) {
    const int e = (blockIdx.x * 256 + threadIdx.x) * 4;
    float4 v;
    unsigned short* dst;
    if (e < 65536) { v = *(const float4*)(Qw + e);           dst = QwB + e; }
    else           { v = *(const float4*)(Ww + (e - 65536)); dst = WwB + (e - 65536); }
    ushort4 s;
    s.x = f2bf(v.x); s.y = f2bf(v.y); s.z = f2bf(v.z); s.w = f2bf(v.w);
    *(ushort4*)dst = s;
}

// ---------------------------------------------------------------------------
// Kernel 1: q = fp8(relu(h @ Qw.T + Qb)).  M=100000 N=256(full) K=256.
// v8 EXACT (round-0, measured 60.4 µs): 64x256 block, 4 waves (wave 64x64),
// A staged sync fp32->bf16 into XOR-swizzled LDS, B-frags streamed from QwB
// with 2-deep register dbuf, 2 barriers/block, fp8 epilogue via per-wave LDS
// quadrant -> sector-complete uint4 stores.
// ---------------------------------------------------------------------------
__global__ __launch_bounds__(256)
void qgemm(const float* __restrict__ h, const unsigned short* __restrict__ QwB,
           const float* __restrict__ Qb, unsigned char* __restrict__ q) {
    __shared__ unsigned short ldsA[64 * 256];   // 32 KB; reused as fp8 epi tile

    const int tid  = threadIdx.x;
    const int row0 = blockIdx.x * 64;
    const int lane = tid & 63;
    const int wv   = tid >> 6;
    const int wc   = wv << 6;              // wave's 64-col (n) slice
    const int quad = lane >> 4;
    const int fr   = lane & 15;

    // --- Stage A: 64 h-rows fp32 -> bf16 -> swizzled LDS (2048 8-elem chunks).
#pragma unroll
    for (int i = 0; i < 8; ++i) {
        const int C = tid + i * 256;
        const int r = C >> 5;
        const int c = C & 31;
        const int gr = min(row0 + r, M_TOTAL - 1);
        const float4 p0 = *(const float4*)(h + (size_t)gr * IN_F + c * 8);
        const float4 p1 = *(const float4*)(h + (size_t)gr * IN_F + c * 8 + 4);
        *(bf16x8*)(ldsA + r * 256 + ((c ^ (r & 7)) * 8)) = cvt_frag(p0, p1);
    }
    // bias for this lane's 4 n-columns (one per nt), loaded while staging lands
    float bias[4];
#pragma unroll
    for (int nt = 0; nt < 4; ++nt) bias[nt] = Qb[wc + nt * 16 + fr];
    __syncthreads();

    floatx4 acc[4][4];
#pragma unroll
    for (int i = 0; i < 4; ++i)
#pragma unroll
        for (int j = 0; j < 4; ++j)
            acc[i][j] = (floatx4){0.f, 0.f, 0.f, 0.f};

    // B-frag base: row n = wc + nt*16 + fr, k-chunk = kb*4 + quad.
    const unsigned short* bp = QwB + (size_t)(wc + fr) * IN_F + quad * 8;

    bf16x8 bvp[2][4];
#pragma unroll
    for (int nt = 0; nt < 4; ++nt)
        bvp[0][nt] = *(const bf16x8*)(bp + nt * 16 * IN_F);

#pragma unroll
    for (int kb = 0; kb < 8; ++kb) {       // K=256, 32/step — no barriers
        const int cur = kb & 1;
        if (kb < 7) {
#pragma unroll
            for (int nt = 0; nt < 4; ++nt)
                bvp[cur ^ 1][nt] = *(const bf16x8*)(bp + nt * 16 * IN_F + (kb + 1) * 32);
        }
        bf16x8 av[4];
#pragma unroll
        for (int mt = 0; mt < 4; ++mt) {
            const int r = mt * 16 + fr;
            const int c = kb * 4 + quad;
            av[mt] = *(const bf16x8*)(ldsA + r * 256 + ((c ^ (r & 7)) * 8));
        }
#pragma unroll
        for (int mt = 0; mt < 4; ++mt)
#pragma unroll
            for (int nt = 0; nt < 4; ++nt)
                acc[mt][nt] = __builtin_amdgcn_mfma_f32_16x16x32_bf16(av[mt], bvp[cur][nt], acc[mt][nt], 0, 0, 0);
    }

    // --- Epilogue: all waves done reading ldsA, then reuse it as fp8 tile.
    __syncthreads();
    unsigned char* const epi = (unsigned char*)ldsA + wv * 4096;   // 64r x 64c
#pragma unroll
    for (int mt = 0; mt < 4; ++mt)
#pragma unroll
        for (int nt = 0; nt < 4; ++nt)
#pragma unroll
            for (int r = 0; r < 4; ++r) {
                float v = acc[mt][nt][r] + bias[nt];
                v = v > 0.f ? v : 0.f;
                epi[(mt * 16 + quad * 4 + r) * 64 + nt * 16 + fr] =
                    (unsigned char)(__builtin_amdgcn_cvt_pk_fp8_f32(v, 0.f, 0, false) & 0xff);
            }
    __asm volatile("s_waitcnt lgkmcnt(0)" ::: "memory");   // in-wave write->read order

    // Sector-complete stores: 16 rows x 4 x 16B segments per instruction.
#pragma unroll
    for (int i = 0; i < 4; ++i) {
        const int r   = i * 16 + (lane >> 2);
        const int seg = lane & 3;
        const uint4 val = *(const uint4*)(epi + r * 64 + seg * 16);
        const int gr = row0 + r;
        if (gr < M_TOTAL)
            *(uint4*)(q + (size_t)gr * HID_F + wc + seg * 16) = val;
    }
}

// ---------------------------------------------------------------------------
// Kernel 2: aggF[n] = sum_t w[n,t]*q[nb[n,t]] / sum_t w[n,t]  (fp32 out).
// One wave/node; 4 neighbors per load instruction (quarter-wave each,
// 16B/lane uint4). 13 iterations (t = 4i + sub, lanes with t>=50 carry w=0).
// ---------------------------------------------------------------------------
__global__ __launch_bounds__(256)
void aggk(const unsigned char* __restrict__ q, const int* __restrict__ nb,
          const float* __restrict__ w, float* __restrict__ aggF) {
    const int node = blockIdx.x * 4 + (threadIdx.x >> 6);
    const int lane = threadIdx.x & 63;

    int   idx_l = 0;
    float w_l   = 0.f;
    if (lane < T_NB) {
        idx_l = nb[(size_t)node * T_NB + lane];
        w_l   = w[(size_t)node * T_NB + lane];
    }
    float sw = w_l;
#pragma unroll
    for (int off = 32; off > 0; off >>= 1)
        sw += __shfl_xor(sw, off, 64);

    const int sub = lane >> 4;       // neighbor slot within group of 4
    const int cg  = lane & 15;       // which 16B column chunk of the row
    float a[16];
#pragma unroll
    for (int j = 0; j < 16; ++j) a[j] = 0.f;

#pragma unroll
    for (int i = 0; i < 13; ++i) {
        const int   t   = 4 * i + sub;              // 0..51; t>=50 has w=0,idx=0
        const int   idx = __shfl(idx_l, t, 64);
        const float wt  = __shfl(w_l, t, 64);
        const uint4 u   = *(const uint4*)(q + (size_t)idx * HID_F + cg * 16);
        v2f p;
        p = __builtin_amdgcn_cvt_pk_f32_fp8(u.x, false); a[0]  += wt * p[0]; a[1]  += wt * p[1];
        p = __builtin_amdgcn_cvt_pk_f32_fp8(u.x, true);  a[2]  += wt * p[0]; a[3]  += wt * p[1];
        p = __builtin_amdgcn_cvt_pk_f32_fp8(u.y, false); a[4]  += wt * p[0]; a[5]  += wt * p[1];
        p = __builtin_amdgcn_cvt_pk_f32_fp8(u.y, true);  a[6]  += wt * p[0]; a[7]  += wt * p[1];
        p = __builtin_amdgcn_cvt_pk_f32_fp8(u.z, false); a[8]  += wt * p[0]; a[9]  += wt * p[1];
        p = __builtin_amdgcn_cvt_pk_f32_fp8(u.z, true);  a[10] += wt * p[0]; a[11] += wt * p[1];
        p = __builtin_amdgcn_cvt_pk_f32_fp8(u.w, false); a[12] += wt * p[0]; a[13] += wt * p[1];
        p = __builtin_amdgcn_cvt_pk_f32_fp8(u.w, true);  a[14] += wt * p[0]; a[15] += wt * p[1];
    }
    // lanes {cg, cg+16, cg+32, cg+48} hold partial sums of the same 16 cols
#pragma unroll
    for (int j = 0; j < 16; ++j) {
        a[j] += __shfl_xor(a[j], 16, 64);
        a[j] += __shfl_xor(a[j], 32, 64);
    }

    if (lane < 16) {
        const float inv = 1.0f / sw;
        float* dst = aggF + (size_t)node * HID_F + cg * 16;
#pragma unroll
        for (int k = 0; k < 4; ++k) {
            float4 o = make_float4(a[4 * k] * inv, a[4 * k + 1] * inv,
                                   a[4 * k + 2] * inv, a[4 * k + 3] * inv);
            *(float4*)(dst + 4 * k) = o;
        }
    }
}

// ---------------------------------------------------------------------------
// Kernel 3: out = normalize(relu(concat(h[nodeset], aggF) @ Ww.T + Wb)).
// M=20000 N=256(full) K=512. 64x256 block, 4 waves (wave = 64 rows x 64 cols,
// acc 4x4), BK=64, async staging (A gathered f32 16KB, B bf16 32KB, both
// XOR-pre-swizzled source addrs -> linear LDS dest). Row L2-norm FUSED:
// per-lane ss -> shfl_xor{1,2,4,8} (16 fr-cols, stays in quad) -> per-wave
// LDS vector -> cross-wave sum + rsqrt -> scaled store. normk deleted.
// ---------------------------------------------------------------------------
__global__ __launch_bounds__(256)
void fgemm(const float* __restrict__ h, const int* __restrict__ nodeset,
           const float* __restrict__ aggF, const unsigned short* __restrict__ WwB,
           const float* __restrict__ Wb, float* __restrict__ out) {
    __shared__ char smem[50432];
    float* ldsA = (float*)smem;                              // 64 rows x 16 chunks (16B)
    unsigned short* ldsB = (unsigned short*)(smem + 16384);  // 256 rows x 8 chunks (16B)
    float* ssbuf = (float*)(smem + 49152);                   // [4][64] per-wave row-ss
    float* ssinv = (float*)(smem + 49152 + 1024);            // [64]

    const int tid  = threadIdx.x;
    const int row0 = blockIdx.x * 64;
    const int lane = tid & 63;
    const int wv   = tid >> 6;
    const int wc   = wv << 6;          // wave's 64-col slice of N=256
    const int fr   = lane & 15;
    const int quad = lane >> 4;

    int nsrow[4];
#pragma unroll
    for (int i = 0; i < 4; ++i) {
        const int row = (tid + i * 256) >> 4;
        nsrow[i] = nodeset[min(row0 + row, N_NODES - 1)];
    }
    float bias[4];
#pragma unroll
    for (int nt = 0; nt < 4; ++nt) bias[nt] = Wb[wc + nt * 16 + fr];

    floatx4 acc[4][4];
#pragma unroll
    for (int i = 0; i < 4; ++i)
#pragma unroll
        for (int j = 0; j < 4; ++j)
            acc[i][j] = (floatx4){0.f, 0.f, 0.f, 0.f};

    for (int kb = 0; kb < 8; ++kb) {
        if (kb) __syncthreads();
        // A: 64 rows x 64 k f32 (16 chunks/row), source-swizzled c^(row&15).
#pragma unroll
        for (int i = 0; i < 4; ++i) {
            const int L   = tid + i * 256;
            const int row = L >> 4;
            const int cg  = (L & 15) ^ (row & 15);
            const float* src = (kb < 4)
                ? h    + (size_t)nsrow[i] * IN_F + kb * 64 + cg * 4
                : aggF + (size_t)min(row0 + row, N_NODES - 1) * HID_F + (kb - 4) * 64 + cg * 4;
            gload16(src, smem + L * 16);
        }
        // B: 256 n-rows x 64 k bf16 (8 chunks/row), source-swizzled c^(row&7).
#pragma unroll
        for (int i = 0; i < 8; ++i) {
            const int L   = tid + i * 256;
            const int row = L >> 3;
            const int cg  = (L & 7) ^ (row & 7);
            gload16(WwB + (size_t)row * KCAT + kb * 64 + cg * 8, smem + 16384 + L * 16);
        }
        __syncthreads();

#pragma unroll
        for (int ks = 0; ks < 2; ++ks) {
            bf16x8 av[4], bv[4];
#pragma unroll
            for (int mt = 0; mt < 4; ++mt) {
                const int row = mt * 16 + fr;
                const int sw  = row & 15;
                const int c0  = ks * 8 + quad * 2;
                const float4 p0 = *(const float4*)(ldsA + (row * 16 + (c0 ^ sw)) * 4);
                const float4 p1 = *(const float4*)(ldsA + (row * 16 + ((c0 + 1) ^ sw)) * 4);
                av[mt] = cvt_frag(p0, p1);
            }
#pragma unroll
            for (int nt = 0; nt < 4; ++nt) {
                const int row = wc + nt * 16 + fr;
                const int sw  = row & 7;
                bv[nt] = *reinterpret_cast<const bf16x8*>(ldsB + row * 64 + (((ks * 4 + quad) ^ sw) * 8));
            }
#pragma unroll
            for (int mt = 0; mt < 4; ++mt)
#pragma unroll
                for (int nt = 0; nt < 4; ++nt)
                    acc[mt][nt] = __builtin_amdgcn_mfma_f32_16x16x32_bf16(av[mt], bv[nt], acc[mt][nt], 0, 0, 0);
        }
    }

    // --- Fused epilogue: bias+relu, row sum-of-squares, normalize, store.
    // Lane owns rows mt*16 + quad*4 + r, cols wc + nt*16 + fr.
    float ssl[16];
#pragma unroll
    for (int j = 0; j < 16; ++j) ssl[j] = 0.f;
#pragma unroll
    for (int mt = 0; mt < 4; ++mt)
#pragma unroll
        for (int nt = 0; nt < 4; ++nt)
#pragma unroll
            for (int r = 0; r < 4; ++r) {
                float v = acc[mt][nt][r] + bias[nt];
                v = v > 0.f ? v : 0.f;
                acc[mt][nt][r] = v;
                ssl[mt * 4 + r] += v * v;
            }
    // Sum across the 16 fr lanes (xor 1,2,4,8 stays within quad).
#pragma unroll
    for (int j = 0; j < 16; ++j) {
        ssl[j] += __shfl_xor(ssl[j], 1, 64);
        ssl[j] += __shfl_xor(ssl[j], 2, 64);
        ssl[j] += __shfl_xor(ssl[j], 4, 64);
        ssl[j] += __shfl_xor(ssl[j], 8, 64);
    }
    if (fr == 0) {
#pragma unroll
        for (int mt = 0; mt < 4; ++mt)
#pragma unroll
            for (int r = 0; r < 4; ++r)
                ssbuf[wv * 64 + mt * 16 + quad * 4 + r] = ssl[mt * 4 + r];
    }
    __syncthreads();
    if (tid < 64)
        ssinv[tid] = rsqrtf(ssbuf[tid] + ssbuf[64 + tid] + ssbuf[128 + tid] + ssbuf[192 + tid]);
    __syncthreads();

#pragma unroll
    for (int mt = 0; mt < 4; ++mt)
#pragma unroll
        for (int r = 0; r < 4; ++r) {
            const int rl = mt * 16 + quad * 4 + r;
            const int gr = row0 + rl;
            if (gr < N_NODES) {
                const float s = ssinv[rl];
#pragma unroll
                for (int nt = 0; nt < 4; ++nt)
                    out[(size_t)gr * OUT_F + wc + nt * 16 + fr] = acc[mt][nt][r] * s;
            }
        }
}

extern "C" void kernel_launch(void* const* d_in, const int* in_sizes, int n_in,
                              void* d_out, int out_size, void* d_ws, size_t ws_size,
                              hipStream_t stream) {
    const float* h        = (const float*)d_in[0];
    const int*   nodeset  = (const int*)d_in[1];
    const int*   nb_nodes = (const int*)d_in[2];
    const float* nb_w     = (const float*)d_in[3];
    const float* Qw       = (const float*)d_in[4];
    const float* Qb       = (const float*)d_in[5];
    const float* Ww       = (const float*)d_in[6];
    const float* Wb       = (const float*)d_in[7];
    float* out = (float*)d_out;

    unsigned char*  q    = (unsigned char*)d_ws;                          // 25.6 MB
    float*          aggF = (float*)((char*)d_ws + 25600000);              // 20.48 MB
    unsigned short* QwB  = (unsigned short*)((char*)d_ws + 46080000);     // 128 KB
    unsigned short* WwB  = (unsigned short*)((char*)d_ws + 46211072);     // 256 KB

    wcvt <<<dim3(192),                 256, 0, stream>>>(Qw, Ww, QwB, WwB);
    qgemm<<<dim3((M_TOTAL + 63) / 64), 256, 0, stream>>>(h, QwB, Qb, q);
    aggk <<<dim3(N_NODES / 4),         256, 0, stream>>>(q, nb_nodes, nb_w, aggF);
    fgemm<<<dim3((N_NODES + 63) / 64), 256, 0, stream>>>(h, nodeset, aggF, WwB, Wb, out);
}